// Round 13
// baseline (486.767 us; speedup 1.0000x reference)
//
#include <hip/hip_runtime.h>

#define LRELU_SLOPE 0.01f
#define BN_EPS 1e-5f

constexpr int B_ = 2, T_ = 8, Z_ = 16, Y_ = 32, X_ = 32;
constexpr int SP   = T_ * Z_ * Y_ * X_;   // 131072
constexpr int NPOS = B_ * SP;             // 262144
constexpr int Tp = 12, Zp = 20, Yp = 36, Xp = 36;   // padded dims (+2 each side)
constexpr int NCB  = 1024;                // conv blocks: b2 * t8 * z16 * yq4
constexpr size_t VOLE = (size_t)B_ * Tp * Zp * Yp * Xp * 16;  // shorts per 16-ch padded vol

typedef float v4f  __attribute__((ext_vector_type(4)));
typedef __bf16 v8bf __attribute__((ext_vector_type(8)));
typedef short  v8s  __attribute__((ext_vector_type(8)));

static __device__ __forceinline__ float bf2f(short s) {
    unsigned int u = ((unsigned int)(unsigned short)s) << 16;
    float f; __builtin_memcpy(&f, &u, 4); return f;
}
static __device__ __forceinline__ short f2bf(float f) {
    unsigned int u; __builtin_memcpy(&u, &f, 4);
    u += 0x7FFF + ((u >> 16) & 1);
    return (short)(u >> 16);
}
static __device__ __forceinline__ v4f mfma16(v8bf a, v8bf b, v4f c) {
    return __builtin_amdgcn_mfma_f32_16x16x32_bf16(a, b, c, 0, 0, 0);
}
// async global->LDS DMA, 16 B/lane; LDS dest = wave-uniform base + lane*16
// (our staging is exactly linear: off = tid*8 shorts). Exec-masked lanes
// (off >= SLAB tail) neither load nor write.  [r9: 171.8 -> 158.7 us/conv]
static __device__ __forceinline__ void gload16(const short* g, short* l) {
    __builtin_amdgcn_global_load_lds(
        (const __attribute__((address_space(1))) void*)g,
        (__attribute__((address_space(3))) void*)l, 16, 0, 0);
}

// ------------------------------------------------------------ weight repack (all 3 layers, 1 dispatch)
// W[co][ci][625] fp32 -> WB[cih][o 626][co][16ci] bf16 (o==625 = zero block)
constexpr int RN1 = 1 * 626 * 16 * 16;   // 160256
constexpr int RN2 = 1 * 626 * 32 * 16;   // 320512
constexpr int RN3 = 2 * 626 * 16 * 16;   // 320512
constexpr int RNT = RN1 + RN2 + RN3;     // 801280 = 3130 * 256
__global__ void repack_all(const float* __restrict__ W1, const float* __restrict__ W2,
                           const float* __restrict__ W3, short* __restrict__ WB1,
                           short* __restrict__ WB2, short* __restrict__ WB3) {
    int i = blockIdx.x * 256 + threadIdx.x;
    if (i >= RNT) return;
    const float* W; short* WB; int CO, CIH, idx;
    if (i < RN1)            { W = W1; WB = WB1; CO = 16; CIH = 1; idx = i; }
    else if (i < RN1 + RN2) { W = W2; WB = WB2; CO = 32; CIH = 1; idx = i - RN1; }
    else                    { W = W3; WB = WB3; CO = 16; CIH = 2; idx = i - RN1 - RN2; }
    int cih = idx / (626 * CO * 16);
    int r   = idx % (626 * CO * 16);
    int o   = r / (CO * 16);
    int rr  = r % (CO * 16);
    int co = rr / 16, cil = rr % 16;
    WB[idx] = (o == 625) ? (short)0
            : f2bf(W[((size_t)co * (CIH * 16) + cih * 16 + cil) * 625 + o]);
}

// ------------------------------------------------------------ embed -> padded bf16 channel-last
__global__ void embed_kernel(const float* __restrict__ x, const float* __restrict__ wemb,
                             const float* __restrict__ bemb, short* __restrict__ outp) {
    int g = blockIdx.x * 256 + threadIdx.x;
    const float* xr = x + (size_t)g * 8;
    // vectorized: 2x float4 (32B-aligned; G13)
    float4 xa = *(const float4*)(xr);
    float4 xb = *(const float4*)(xr + 4);
    float xv[8] = {xa.x, xa.y, xa.z, xa.w, xb.x, xb.y, xb.z, xb.w};
    int xx = g & 31, yy = (g >> 5) & 31, zz = (g >> 10) & 15, tt = (g >> 14) & 7, bb = g >> 17;
    size_t addr = ((((size_t)(bb * Tp + tt + 2) * Zp + zz + 2) * Yp + yy + 2) * Xp + xx + 2) * 16;
    short ov[16];
#pragma unroll
    for (int c = 0; c < 16; ++c) {
        float a = bemb[c];
#pragma unroll
        for (int f = 0; f < 8; ++f) a = fmaf(xv[f], wemb[f * 16 + c], a);
        ov[c] = f2bf(a);
    }
    *(v8s*)(outp + addr)     = *(v8s*)ov;
    *(v8s*)(outp + addr + 8) = *(v8s*)(ov + 8);
}

// ------------------------------------------------------------ conv4d: dbuf LDS slab, 1 barrier/phase
// FINAL composition (r11 structure — best measured conv dispatches 156.5 us):
// DMA staging (r9, +8%) + balance swizzle & setprio (r2, +8%) + NT==1 weight
// hoist/fence (r11, +1.4%). Falsified: CO-split (r3,r10), rotation (r3),
// YT=4 (r6,r7), BN-fusion-in-staging (r8), compressed valid loop (r12).
// Cycle model: per CU phase-slot ~2500 cyc, MFMA demand ~1164 -> MfmaUtil
// ~45% is this 2-barrier schedule's ceiling; DMA latency (200-900 cyc) is
// fully hidden under the phase, so counted-vmcnt pipelining has no stall to
// remove (T3/T4 prerequisite absent).
// Block (256 thr, 4 waves) = (b,t,z,yq): out y in [yq*8,+8), x 0..31, all
// CO. Slabs s=(kt,kz)[,cih]: 25*CIH planes of 12y x 36x x 16ci (pads
// pre-zeroed in global). Double-buffered: stage slab s+1 into buf (s+1)&1 at
// top of phase s; ONE sync per phase. Wave = (xh, yw): 16x x 4y.
// Balance swizzle (verified bijective): co-resident quads sweep s4=0..3 with
// t=T0+2*s4 (sum w_t==17), z=Z0+4*s4 -> per-CU slab sums in [75,82].
template <int CI, int CO>
__global__ __launch_bounds__(256, 4) void conv_mfma(
        const short* __restrict__ inp,   // CIH padded vols, stride VOLE
        const short* __restrict__ wb,    // bf16 [CIH][626][CO][16]
        const float* __restrict__ bias,
        short* __restrict__ outp,        // CO/16 padded vols, stride VOLE
        float* __restrict__ ps, float* __restrict__ psq) {
    constexpr int NT = CO / 16;
    constexpr int CIH = CI / 16;
    constexpr int NS = 25 * CIH;
    constexpr int SLAB = 12 * 36 * 16;           // 6912 shorts
    constexpr int SLABP = SLAB + 16;             // +16: dummy-lane read overflow
    __shared__ short As[2 * SLABP];
    __shared__ float lsum[32], lsq[32];

    const int tid = threadIdx.x;
    const int w = tid >> 6, lane = tid & 63;
    const int q = lane >> 4, m = lane & 15;
    const int xh = w & 1, yw = w >> 1;
    const int blk = blockIdx.x;
    const int xl  = blk & 7;                     // XCD (round-robin model)
    const int j   = blk >> 3;                    // within-XCD index, 7 bits
    const int s4  = ((j & 3) + (j >> 5)) & 3;    // sweeps 0..3 in co-resident quads
    const int t   = (((j >> 2) & 7) + 2 * s4) & 7;
    const int z   = (((xl << 1) | ((j >> 5) & 1)) + 4 * s4) & 15;
    const int b   = j >> 6;
    const int yq  = s4;

    const int ci0 = (q & 1) * 8;
    const int sel = q >> 1;

    if (tid < 4) *(v8s*)(As + (tid >> 1) * SLABP + SLAB + (tid & 1) * 8) =
        (v8s){0,0,0,0,0,0,0,0};

    v4f acc[4][NT];
#pragma unroll
    for (int al = 0; al < 4; ++al)
#pragma unroll
        for (int nt = 0; nt < NT; ++nt) acc[al][nt] = (v4f){0.f, 0.f, 0.f, 0.f};

    auto sdec = [&](int s, int& cih, int& kt, int& kz) {
        int sl = (CIH == 2) ? (s >> 1) : s;
        cih = (CIH == 2) ? (s & 1) : 0;
        kt = sl / 5; kz = sl % 5;
    };
    auto slab_ok = [&](int s) -> bool {
        int cih, kt, kz; sdec(s, cih, kt, kz);
        int tt = t + kt, zz = z + kz;
        return tt >= 2 && tt < 10 && zz >= 2 && zz < 18;
    };
    auto stage = [&](int s, int slot) {
        int cih, kt, kz; sdec(s, cih, kt, kz);
        const short* gA = inp + (size_t)cih * VOLE +
            (((size_t)(b * Tp + t + kt) * Zp + (z + kz)) * Yp + yq * 8) * (size_t)(Xp * 16);
        short* dA = As + slot * SLABP;
#pragma unroll
        for (int r2 = 0; r2 < 4; ++r2) {
            int off = tid * 8 + r2 * 2048;
            if (off < SLAB) gload16(gA + off, dA + off);
        }
    };

    if (slab_ok(0)) stage(0, 0);
    __syncthreads();

#pragma unroll 1
    for (int s = 0; s < NS; ++s) {
        const bool nok = (s + 1 < NS) && slab_ok(s + 1);
        if (nok) stage(s + 1, (s + 1) & 1);      // DMA overlaps this phase's compute

        if (slab_ok(s)) {
            int cih, kt, kz; sdec(s, cih, kt, kz);
            const int obase = (kt * 5 + kz) * 25;
            const short* wbc = wb + (size_t)cih * 626 * (CO * 16);
            const short* Ab = As + (s & 1) * SLABP;
            __builtin_amdgcn_s_setprio(1);
            if constexpr (NT == 1) {
                // one latency window: 15 loads in flight, fenced so they
                // cannot sink back to their uses
                v8bf Bfall[15];
#pragma unroll
                for (int g = 0; g < 3; ++g) {
#pragma unroll
                    for (int ky = 0; ky < 5; ++ky) {
                        const int o0 = obase + ky * 5 + 2 * g;
                        const int od = (g < 2) ? 1 : (625 - o0);
                        const int oq = o0 + sel * od;
                        Bfall[g * 5 + ky] = *(const v8bf*)(wbc + (size_t)oq * (CO * 16) +
                                                           m * 16 + ci0);
                    }
                }
                __builtin_amdgcn_sched_barrier(0);
#pragma unroll
                for (int g = 0; g < 3; ++g) {
                    const int ax = xh * 16 + m + 2 * g + sel;
#pragma unroll
                    for (int rl = 0; rl < 8; ++rl) {
                        v8bf Af = *(const v8bf*)(Ab + ((yw * 4 + rl) * 36 + ax) * 16 + ci0);
#pragma unroll
                        for (int ky = 0; ky < 5; ++ky) {
                            const int al = rl - ky;
                            if (al >= 0 && al < 4)
                                acc[al][0] = mfma16(Af, Bfall[g * 5 + ky], acc[al][0]);
                        }
                    }
                }
            } else {
#pragma unroll
                for (int g = 0; g < 3; ++g) {
                    const int kx0 = 2 * g;
                    v8bf Bf[5][NT];
#pragma unroll
                    for (int ky = 0; ky < 5; ++ky) {
                        const int o0 = obase + ky * 5 + kx0;
                        const int od = (g < 2) ? 1 : (625 - o0);
                        const int oq = o0 + sel * od;
#pragma unroll
                        for (int nt = 0; nt < NT; ++nt)
                            Bf[ky][nt] = *(const v8bf*)(wbc + (size_t)oq * (CO * 16) +
                                                        (nt * 16 + m) * 16 + ci0);
                    }
                    const int ax = xh * 16 + m + kx0 + sel;
#pragma unroll
                    for (int rl = 0; rl < 8; ++rl) {
                        v8bf Af = *(const v8bf*)(Ab + ((yw * 4 + rl) * 36 + ax) * 16 + ci0);
#pragma unroll
                        for (int ky = 0; ky < 5; ++ky) {
                            const int al = rl - ky;
                            if (al >= 0 && al < 4) {
#pragma unroll
                                for (int nt = 0; nt < NT; ++nt)
                                    acc[al][nt] = mfma16(Af, Bf[ky][nt], acc[al][nt]);
                            }
                        }
                    }
                }
            }
            __builtin_amdgcn_s_setprio(0);
        }
        __syncthreads();                          // drains vmcnt: slab s+1 landed
    }

    // ---- epilogue: bias, bf16 store (raw) to NT padded vols, block stats
    if (tid < 32) { lsum[tid] = 0.f; lsq[tid] = 0.f; }
    __syncthreads();

    const int ybase = yq * 8 + yw * 4;
#pragma unroll
    for (int nt = 0; nt < NT; ++nt) {
        const int co = nt * 16 + m;
        const float bv = bias[co];
        float s = 0.f, sq = 0.f;
#pragma unroll
        for (int al = 0; al < 4; ++al) {
            const size_t orow = (size_t)nt * VOLE +
                ((((size_t)(b * Tp + t + 2) * Zp + (z + 2)) * Yp +
                  (ybase + al + 2)) * Xp + (xh * 16 + 2)) * 16;
#pragma unroll
            for (int rg = 0; rg < 4; ++rg) {
                float v = acc[al][nt][rg] + bv;
                outp[orow + (size_t)(q * 4 + rg) * 16 + m] = f2bf(v);
                s += v; sq += v * v;
            }
        }
        s += __shfl_down(s, 32, 64);  sq += __shfl_down(sq, 32, 64);
        s += __shfl_down(s, 16, 64);  sq += __shfl_down(sq, 16, 64);
        if (lane < 16) { atomicAdd(&lsum[co], s); atomicAdd(&lsq[co], sq); }
    }
    __syncthreads();
    if (tid < CO) {
        ps[(size_t)tid * NCB + blk]  = lsum[tid];
        psq[(size_t)tid * NCB + blk] = lsq[tid];
    }
}

// ------------------------------------------------------------ bn stats: fold into scale/shift
__global__ void stats_kernel(const float* __restrict__ ps, const float* __restrict__ psq,
                             const float* __restrict__ g, const float* __restrict__ beta,
                             float* __restrict__ scale, float* __restrict__ shift) {
    int co = blockIdx.x;
    int tid = threadIdx.x;
    float s = 0.f, q = 0.f;
    for (int i = tid; i < NCB; i += 256) {
        s += ps[(size_t)co * NCB + i];
        q += psq[(size_t)co * NCB + i];
    }
#pragma unroll
    for (int off = 32; off >= 1; off >>= 1) {
        s += __shfl_down(s, off, 64);
        q += __shfl_down(q, off, 64);
    }
    __shared__ float ss[4], qq[4];
    int w = tid >> 6, lane = tid & 63;
    if (lane == 0) { ss[w] = s; qq[w] = q; }
    __syncthreads();
    if (tid == 0) {
        float S = ss[0] + ss[1] + ss[2] + ss[3];
        float Q = qq[0] + qq[1] + qq[2] + qq[3];
        float mn = S / (float)NPOS;
        float var = Q / (float)NPOS - mn * mn;
        float rstd = rsqrtf(var + BN_EPS);
        float sc = g[co] * rstd;
        scale[co] = sc;
        shift[co] = beta[co] - mn * sc;
    }
}

// ------------------------------------------------------------ bn + leaky relu, in-place interior
// of NV consecutive 16-ch vols (one dispatch for a 32-ch split pair).
// grid = NV * 2*NPOS / 256; voli = g>>19 (2*NPOS = 2^19).
__global__ void bn_lrelu16(short* __restrict__ vol, const float* __restrict__ scale,
                           const float* __restrict__ shift) {
    int g = blockIdx.x * 256 + threadIdx.x;
    int voli = g >> 19;
    int gg = g & ((1 << 19) - 1);
    int half = gg & 1, p = gg >> 1;
    int xx = p & 31, yy = (p >> 5) & 31, zz = (p >> 10) & 15, tt = (p >> 14) & 7, bb = p >> 17;
    size_t addr = (size_t)voli * VOLE +
        ((((size_t)(bb * Tp + tt + 2) * Zp + zz + 2) * Yp + yy + 2) * Xp + xx + 2) * 16
        + half * 8;
    const int c0 = voli * 16 + half * 8;
    v8s v = *(v8s*)(vol + addr);
    short o[8];
#pragma unroll
    for (int j = 0; j < 8; ++j) {
        float f = bf2f(v[j]) * scale[c0 + j] + shift[c0 + j];
        f = f > 0.f ? f : LRELU_SLOPE * f;
        o[j] = f2bf(f);
    }
    *(v8s*)(vol + addr) = *(v8s*)o;
}

// ------------------------------------------------------------ final: bn3 + lrelu + projection
__global__ void bnproj_kernel(const short* __restrict__ h, const float* __restrict__ scale,
                              const float* __restrict__ shift, const float* __restrict__ wp,
                              const float* __restrict__ bp, float* __restrict__ out) {
    int g = blockIdx.x * 256 + threadIdx.x;
    int xx = g & 31, yy = (g >> 5) & 31, zz = (g >> 10) & 15, tt = (g >> 14) & 7, bb = g >> 17;
    size_t addr = ((((size_t)(bb * Tp + tt + 2) * Zp + zz + 2) * Yp + yy + 2) * Xp + xx + 2) * 16;
    v8s lo = *(const v8s*)(h + addr);
    v8s hi = *(const v8s*)(h + addr + 8);
    float a = bp[0];
#pragma unroll
    for (int j = 0; j < 8; ++j) {
        float f = bf2f(lo[j]) * scale[j] + shift[j];
        f = f > 0.f ? f : LRELU_SLOPE * f;
        a = fmaf(f, wp[j], a);
    }
#pragma unroll
    for (int j = 0; j < 8; ++j) {
        float f = bf2f(hi[j]) * scale[8 + j] + shift[8 + j];
        f = f > 0.f ? f : LRELU_SLOPE * f;
        a = fmaf(f, wp[8 + j], a);
    }
    out[g] = a;
}

// ------------------------------------------------------------ launch
extern "C" void kernel_launch(void* const* d_in, const int* in_sizes, int n_in,
                              void* d_out, int out_size, void* d_ws, size_t ws_size,
                              hipStream_t stream) {
    const float* x    = (const float*)d_in[0];
    const float* wemb = (const float*)d_in[1];
    const float* bemb = (const float*)d_in[2];
    const float* W1   = (const float*)d_in[3];
    const float* b1   = (const float*)d_in[4];
    const float* g1   = (const float*)d_in[5];
    const float* be1  = (const float*)d_in[6];
    const float* W2   = (const float*)d_in[7];
    const float* b2   = (const float*)d_in[8];
    const float* g2   = (const float*)d_in[9];
    const float* be2  = (const float*)d_in[10];
    const float* W3   = (const float*)d_in[11];
    const float* b3   = (const float*)d_in[12];
    const float* g3   = (const float*)d_in[13];
    const float* be3  = (const float*)d_in[14];
    const float* wp   = (const float*)d_in[15];
    const float* bp   = (const float*)d_in[16];

    char* base = (char*)d_ws;
    short* PA   = (short*)(base);                  // 16-ch vol: 19,906,560 B
    short* PB   = (short*)(base + 19906560);       // 16-ch vol: 19,906,560 B
    short* P32  = (short*)(base + 39813120);       // 2 vols: 39,813,120 B
    short* WB1  = (short*)(base + 79626240);       // 320,512 B
    short* WB2  = (short*)(base + 79946752);       // 641,024 B
    short* WB3  = (short*)(base + 80587776);       // 641,024 B
    float* ps   = (float*)(base + 81228800);       // 32*1024*4 = 131,072 B
    float* psq  = (float*)(base + 81359872);       // 131,072 B
    float* sc1  = (float*)(base + 81490944);       // 128 B each
    float* sh1  = (float*)(base + 81491072);
    float* sc2  = (float*)(base + 81491200);
    float* sh2  = (float*)(base + 81491328);
    float* sc3  = (float*)(base + 81491456);
    float* sh3  = (float*)(base + 81491584);

    // zero all padded activation volumes (pads must be 0 every call;
    // staging relies on it -> conv staging is a raw copy, no masking)
    hipMemsetAsync(base, 0, 79626240, stream);

    repack_all<<<(RNT + 255) / 256, 256, 0, stream>>>(W1, W2, W3, WB1, WB2, WB3);

    embed_kernel<<<NPOS / 256, 256, 0, stream>>>(x, wemb, bemb, PA);

    // layer 1: 16 -> 16
    conv_mfma<16, 16><<<NCB, 256, 0, stream>>>(PA, WB1, b1, PB, ps, psq);
    stats_kernel<<<16, 256, 0, stream>>>(ps, psq, g1, be1, sc1, sh1);
    bn_lrelu16<<<2 * NPOS / 256, 256, 0, stream>>>(PB, sc1, sh1);

    // layer 2: 16 -> 32 (output = 2 split 16-ch vols)
    conv_mfma<16, 32><<<NCB, 256, 0, stream>>>(PB, WB2, b2, P32, ps, psq);
    stats_kernel<<<32, 256, 0, stream>>>(ps, psq, g2, be2, sc2, sh2);
    bn_lrelu16<<<4 * NPOS / 256, 256, 0, stream>>>(P32, sc2, sh2);  // both vols, one dispatch

    // layer 3: 32 -> 16 (reads 2 split vols)
    conv_mfma<32, 16><<<NCB, 256, 0, stream>>>(P32, WB3, b3, PA, ps, psq);
    stats_kernel<<<16, 256, 0, stream>>>(ps, psq, g3, be3, sc3, sh3);

    // BN3 + lrelu + projection
    bnproj_kernel<<<NPOS / 256, 256, 0, stream>>>(PA, sc3, sh3, wp, bp, (float*)d_out);
}

// Round 14
// 470.479 us; speedup vs baseline: 1.0346x; 1.0346x over previous
//
#include <hip/hip_runtime.h>

#define LRELU_SLOPE 0.01f
#define BN_EPS 1e-5f

constexpr int B_ = 2, T_ = 8, Z_ = 16, Y_ = 32, X_ = 32;
constexpr int SP   = T_ * Z_ * Y_ * X_;   // 131072
constexpr int NPOS = B_ * SP;             // 262144
constexpr int Tp = 12, Zp = 20, Yp = 36, Xp = 36;   // padded dims (+2 each side)
constexpr int NCB  = 1024;                // conv blocks: b2 * t8 * z16 * yq4
constexpr size_t VOLE = (size_t)B_ * Tp * Zp * Yp * Xp * 16;  // shorts per 16-ch padded vol

typedef float v4f  __attribute__((ext_vector_type(4)));
typedef __bf16 v8bf __attribute__((ext_vector_type(8)));
typedef __bf16 v4bf __attribute__((ext_vector_type(4)));
typedef short  v8s  __attribute__((ext_vector_type(8)));
typedef short  v4s  __attribute__((ext_vector_type(4)));

static __device__ __forceinline__ float bf2f(short s) {
    unsigned int u = ((unsigned int)(unsigned short)s) << 16;
    float f; __builtin_memcpy(&f, &u, 4); return f;
}
static __device__ __forceinline__ short f2bf(float f) {
    unsigned int u; __builtin_memcpy(&u, &f, 4);
    u += 0x7FFF + ((u >> 16) & 1);
    return (short)(u >> 16);
}
static __device__ __forceinline__ v4f mfma16(v8bf a, v8bf b, v4f c) {
    return __builtin_amdgcn_mfma_f32_16x16x32_bf16(a, b, c, 0, 0, 0);
}

// K=16 bf16 MFMA for the unpaired 5th x-tap (kx=4). Removes the o=625
// zero-block multiply (1/6 of NT=1 MFMA FLOP). Fragment layout follows the
// verified K32 pattern scaled: lane l -> m=l&15, k=(l>>4)*4+j (=ci q*4+j).
// Name hedged via __has_builtin; falls back to the proven zero-pad path.
#if __has_builtin(__builtin_amdgcn_mfma_f32_16x16x16_bf16)
#define HAVE_K16 1
static __device__ __forceinline__ v4f mfma_k16(v4s a, v4s b, v4f c) {
    v4bf ab, bb; __builtin_memcpy(&ab, &a, 8); __builtin_memcpy(&bb, &b, 8);
    return __builtin_amdgcn_mfma_f32_16x16x16_bf16(ab, bb, c, 0, 0, 0);
}
#elif __has_builtin(__builtin_amdgcn_mfma_f32_16x16x16bf16_1k)
#define HAVE_K16 1
static __device__ __forceinline__ v4f mfma_k16(v4s a, v4s b, v4f c) {
    return __builtin_amdgcn_mfma_f32_16x16x16bf16_1k(a, b, c, 0, 0, 0);
}
#else
#define HAVE_K16 0
#endif

// async global->LDS DMA, 16 B/lane; LDS dest = wave-uniform base + lane*16
// (our staging is exactly linear: off = tid*8 shorts). Exec-masked lanes
// (off >= SLAB tail) neither load nor write.  [r9: 171.8 -> 158.7 us/conv]
static __device__ __forceinline__ void gload16(const short* g, short* l) {
    __builtin_amdgcn_global_load_lds(
        (const __attribute__((address_space(1))) void*)g,
        (__attribute__((address_space(3))) void*)l, 16, 0, 0);
}

// ------------------------------------------------------------ weight repack (all 3 layers, 1 dispatch)
// W[co][ci][625] fp32 -> WB[cih][o 626][co][16ci] bf16 (o==625 = zero block)
constexpr int RN1 = 1 * 626 * 16 * 16;   // 160256
constexpr int RN2 = 1 * 626 * 32 * 16;   // 320512
constexpr int RN3 = 2 * 626 * 16 * 16;   // 320512
constexpr int RNT = RN1 + RN2 + RN3;     // 801280 = 3130 * 256
__global__ void repack_all(const float* __restrict__ W1, const float* __restrict__ W2,
                           const float* __restrict__ W3, short* __restrict__ WB1,
                           short* __restrict__ WB2, short* __restrict__ WB3) {
    int i = blockIdx.x * 256 + threadIdx.x;
    if (i >= RNT) return;
    const float* W; short* WB; int CO, CIH, idx;
    if (i < RN1)            { W = W1; WB = WB1; CO = 16; CIH = 1; idx = i; }
    else if (i < RN1 + RN2) { W = W2; WB = WB2; CO = 32; CIH = 1; idx = i - RN1; }
    else                    { W = W3; WB = WB3; CO = 16; CIH = 2; idx = i - RN1 - RN2; }
    int cih = idx / (626 * CO * 16);
    int r   = idx % (626 * CO * 16);
    int o   = r / (CO * 16);
    int rr  = r % (CO * 16);
    int co = rr / 16, cil = rr % 16;
    WB[idx] = (o == 625) ? (short)0
            : f2bf(W[((size_t)co * (CIH * 16) + cih * 16 + cil) * 625 + o]);
}

// ------------------------------------------------------------ embed -> padded bf16 channel-last
__global__ void embed_kernel(const float* __restrict__ x, const float* __restrict__ wemb,
                             const float* __restrict__ bemb, short* __restrict__ outp) {
    int g = blockIdx.x * 256 + threadIdx.x;
    const float* xr = x + (size_t)g * 8;
    float4 xa = *(const float4*)(xr);
    float4 xb = *(const float4*)(xr + 4);
    float xv[8] = {xa.x, xa.y, xa.z, xa.w, xb.x, xb.y, xb.z, xb.w};
    int xx = g & 31, yy = (g >> 5) & 31, zz = (g >> 10) & 15, tt = (g >> 14) & 7, bb = g >> 17;
    size_t addr = ((((size_t)(bb * Tp + tt + 2) * Zp + zz + 2) * Yp + yy + 2) * Xp + xx + 2) * 16;
    short ov[16];
#pragma unroll
    for (int c = 0; c < 16; ++c) {
        float a = bemb[c];
#pragma unroll
        for (int f = 0; f < 8; ++f) a = fmaf(xv[f], wemb[f * 16 + c], a);
        ov[c] = f2bf(a);
    }
    *(v8s*)(outp + addr)     = *(v8s*)ov;
    *(v8s*)(outp + addr + 8) = *(v8s*)(ov + 8);
}

// ------------------------------------------------------------ conv4d: dbuf LDS slab, 1 barrier/phase
// Proven composition: DMA staging (r9) + balance swizzle/setprio (r2) +
// NT==1 weight hoist/fence (r11). Falsified: CO-split (r3,r10), rotation
// (r3), YT=4 (r6,r7), BN-fusion (r8), compressed loop (r12).
// THIS ROUND: NT==1 tap-4 via K=16 MFMA — the K32 sel-packing covers taps
// kx={0,1},{2,3} and wasted {4,zero} (1/6 of MFMA FLOP on zero weights).
// Now g=0,1 stay K32; tap kx=4 uses mfma_k16 (A/B = 4 bf16, ci=q*4+j):
// -16.7% matrix-pipe, -17% weight bytes, -8% LDS bytes on conv1/conv3.
// Falls back to the old path if no K16 builtin exists.
// Block (256 thr, 4 waves) = (b,t,z,yq): out y in [yq*8,+8), x 0..31, all
// CO. Slabs s=(kt,kz)[,cih]: 25*CIH planes of 12y x 36x x 16ci (pads
// pre-zeroed in global). Double-buffered: stage slab s+1 into buf (s+1)&1 at
// top of phase s; ONE sync per phase. Wave = (xh, yw): 16x x 4y.
// Balance swizzle (verified bijective): co-resident quads sweep s4=0..3 with
// t=T0+2*s4 (sum w_t==17), z=Z0+4*s4 -> per-CU slab sums in [75,82].
template <int CI, int CO>
__global__ __launch_bounds__(256, 4) void conv_mfma(
        const short* __restrict__ inp,   // CIH padded vols, stride VOLE
        const short* __restrict__ wb,    // bf16 [CIH][626][CO][16]
        const float* __restrict__ bias,
        short* __restrict__ outp,        // CO/16 padded vols, stride VOLE
        float* __restrict__ ps, float* __restrict__ psq) {
    constexpr int NT = CO / 16;
    constexpr int CIH = CI / 16;
    constexpr int NS = 25 * CIH;
    constexpr int SLAB = 12 * 36 * 16;           // 6912 shorts
    constexpr int SLABP = SLAB + 16;             // +16: dummy-lane read overflow
    __shared__ short As[2 * SLABP];
    __shared__ float lsum[32], lsq[32];

    const int tid = threadIdx.x;
    const int w = tid >> 6, lane = tid & 63;
    const int q = lane >> 4, m = lane & 15;
    const int xh = w & 1, yw = w >> 1;
    const int blk = blockIdx.x;
    const int xl  = blk & 7;                     // XCD (round-robin model)
    const int j   = blk >> 3;                    // within-XCD index, 7 bits
    const int s4  = ((j & 3) + (j >> 5)) & 3;    // sweeps 0..3 in co-resident quads
    const int t   = (((j >> 2) & 7) + 2 * s4) & 7;
    const int z   = (((xl << 1) | ((j >> 5) & 1)) + 4 * s4) & 15;
    const int b   = j >> 6;
    const int yq  = s4;

    const int ci0 = (q & 1) * 8;
    const int sel = q >> 1;

    if (tid < 4) *(v8s*)(As + (tid >> 1) * SLABP + SLAB + (tid & 1) * 8) =
        (v8s){0,0,0,0,0,0,0,0};

    v4f acc[4][NT];
#pragma unroll
    for (int al = 0; al < 4; ++al)
#pragma unroll
        for (int nt = 0; nt < NT; ++nt) acc[al][nt] = (v4f){0.f, 0.f, 0.f, 0.f};

    auto sdec = [&](int s, int& cih, int& kt, int& kz) {
        int sl = (CIH == 2) ? (s >> 1) : s;
        cih = (CIH == 2) ? (s & 1) : 0;
        kt = sl / 5; kz = sl % 5;
    };
    auto slab_ok = [&](int s) -> bool {
        int cih, kt, kz; sdec(s, cih, kt, kz);
        int tt = t + kt, zz = z + kz;
        return tt >= 2 && tt < 10 && zz >= 2 && zz < 18;
    };
    auto stage = [&](int s, int slot) {
        int cih, kt, kz; sdec(s, cih, kt, kz);
        const short* gA = inp + (size_t)cih * VOLE +
            (((size_t)(b * Tp + t + kt) * Zp + (z + kz)) * Yp + yq * 8) * (size_t)(Xp * 16);
        short* dA = As + slot * SLABP;
#pragma unroll
        for (int r2 = 0; r2 < 4; ++r2) {
            int off = tid * 8 + r2 * 2048;
            if (off < SLAB) gload16(gA + off, dA + off);
        }
    };

    if (slab_ok(0)) stage(0, 0);
    __syncthreads();

#pragma unroll 1
    for (int s = 0; s < NS; ++s) {
        const bool nok = (s + 1 < NS) && slab_ok(s + 1);
        if (nok) stage(s + 1, (s + 1) & 1);      // DMA overlaps this phase's compute

        if (slab_ok(s)) {
            int cih, kt, kz; sdec(s, cih, kt, kz);
            const int obase = (kt * 5 + kz) * 25;
            const short* wbc = wb + (size_t)cih * 626 * (CO * 16);
            const short* Ab = As + (s & 1) * SLABP;
            __builtin_amdgcn_s_setprio(1);
#if HAVE_K16
            if constexpr (NT == 1) {
                // taps kx=0..3 via 2 K32 groups + tap kx=4 via K16 (no zero pad)
                v8bf Bfall[10];
                v4s  Bf4[5];
#pragma unroll
                for (int g = 0; g < 2; ++g) {
#pragma unroll
                    for (int ky = 0; ky < 5; ++ky) {
                        const int oq = obase + ky * 5 + 2 * g + sel;
                        Bfall[g * 5 + ky] = *(const v8bf*)(wbc + (size_t)oq * (CO * 16) +
                                                           m * 16 + ci0);
                    }
                }
#pragma unroll
                for (int ky = 0; ky < 5; ++ky) {
                    const int o4 = obase + ky * 5 + 4;
                    Bf4[ky] = *(const v4s*)(wbc + (size_t)o4 * (CO * 16) + m * 16 + q * 4);
                }
                __builtin_amdgcn_sched_barrier(0);
#pragma unroll
                for (int g = 0; g < 2; ++g) {
                    const int ax = xh * 16 + m + 2 * g + sel;
#pragma unroll
                    for (int rl = 0; rl < 8; ++rl) {
                        v8bf Af = *(const v8bf*)(Ab + ((yw * 4 + rl) * 36 + ax) * 16 + ci0);
#pragma unroll
                        for (int ky = 0; ky < 5; ++ky) {
                            const int al = rl - ky;
                            if (al >= 0 && al < 4)
                                acc[al][0] = mfma16(Af, Bfall[g * 5 + ky], acc[al][0]);
                        }
                    }
                }
                const int ax4 = xh * 16 + m + 4;
#pragma unroll
                for (int rl = 0; rl < 8; ++rl) {
                    v4s Af4 = *(const v4s*)(Ab + ((yw * 4 + rl) * 36 + ax4) * 16 + q * 4);
#pragma unroll
                    for (int ky = 0; ky < 5; ++ky) {
                        const int al = rl - ky;
                        if (al >= 0 && al < 4)
                            acc[al][0] = mfma_k16(Af4, Bf4[ky], acc[al][0]);
                    }
                }
            } else
#endif
            if constexpr (NT == 1) {
                // fallback: one latency window, 15 loads (tap-4 zero-padded)
                v8bf Bfall[15];
#pragma unroll
                for (int g = 0; g < 3; ++g) {
#pragma unroll
                    for (int ky = 0; ky < 5; ++ky) {
                        const int o0 = obase + ky * 5 + 2 * g;
                        const int od = (g < 2) ? 1 : (625 - o0);
                        const int oq = o0 + sel * od;
                        Bfall[g * 5 + ky] = *(const v8bf*)(wbc + (size_t)oq * (CO * 16) +
                                                           m * 16 + ci0);
                    }
                }
                __builtin_amdgcn_sched_barrier(0);
#pragma unroll
                for (int g = 0; g < 3; ++g) {
                    const int ax = xh * 16 + m + 2 * g + sel;
#pragma unroll
                    for (int rl = 0; rl < 8; ++rl) {
                        v8bf Af = *(const v8bf*)(Ab + ((yw * 4 + rl) * 36 + ax) * 16 + ci0);
#pragma unroll
                        for (int ky = 0; ky < 5; ++ky) {
                            const int al = rl - ky;
                            if (al >= 0 && al < 4)
                                acc[al][0] = mfma16(Af, Bfall[g * 5 + ky], acc[al][0]);
                        }
                    }
                }
            } else {
#pragma unroll
                for (int g = 0; g < 3; ++g) {
                    const int kx0 = 2 * g;
                    v8bf Bf[5][NT];
#pragma unroll
                    for (int ky = 0; ky < 5; ++ky) {
                        const int o0 = obase + ky * 5 + kx0;
                        const int od = (g < 2) ? 1 : (625 - o0);
                        const int oq = o0 + sel * od;
#pragma unroll
                        for (int nt = 0; nt < NT; ++nt)
                            Bf[ky][nt] = *(const v8bf*)(wbc + (size_t)oq * (CO * 16) +
                                                        (nt * 16 + m) * 16 + ci0);
                    }
                    const int ax = xh * 16 + m + kx0 + sel;
#pragma unroll
                    for (int rl = 0; rl < 8; ++rl) {
                        v8bf Af = *(const v8bf*)(Ab + ((yw * 4 + rl) * 36 + ax) * 16 + ci0);
#pragma unroll
                        for (int ky = 0; ky < 5; ++ky) {
                            const int al = rl - ky;
                            if (al >= 0 && al < 4) {
#pragma unroll
                                for (int nt = 0; nt < NT; ++nt)
                                    acc[al][nt] = mfma16(Af, Bf[ky][nt], acc[al][nt]);
                            }
                        }
                    }
                }
            }
            __builtin_amdgcn_s_setprio(0);
        }
        __syncthreads();                          // drains vmcnt: slab s+1 landed
    }

    // ---- epilogue: bias, bf16 store (raw) to NT padded vols, block stats
    if (tid < 32) { lsum[tid] = 0.f; lsq[tid] = 0.f; }
    __syncthreads();

    const int ybase = yq * 8 + yw * 4;
#pragma unroll
    for (int nt = 0; nt < NT; ++nt) {
        const int co = nt * 16 + m;
        const float bv = bias[co];
        float s = 0.f, sq = 0.f;
#pragma unroll
        for (int al = 0; al < 4; ++al) {
            const size_t orow = (size_t)nt * VOLE +
                ((((size_t)(b * Tp + t + 2) * Zp + (z + 2)) * Yp +
                  (ybase + al + 2)) * Xp + (xh * 16 + 2)) * 16;
#pragma unroll
            for (int rg = 0; rg < 4; ++rg) {
                float v = acc[al][nt][rg] + bv;
                outp[orow + (size_t)(q * 4 + rg) * 16 + m] = f2bf(v);
                s += v; sq += v * v;
            }
        }
        s += __shfl_down(s, 32, 64);  sq += __shfl_down(sq, 32, 64);
        s += __shfl_down(s, 16, 64);  sq += __shfl_down(sq, 16, 64);
        if (lane < 16) { atomicAdd(&lsum[co], s); atomicAdd(&lsq[co], sq); }
    }
    __syncthreads();
    if (tid < CO) {
        ps[(size_t)tid * NCB + blk]  = lsum[tid];
        psq[(size_t)tid * NCB + blk] = lsq[tid];
    }
}

// ------------------------------------------------------------ bn stats: fold into scale/shift
__global__ void stats_kernel(const float* __restrict__ ps, const float* __restrict__ psq,
                             const float* __restrict__ g, const float* __restrict__ beta,
                             float* __restrict__ scale, float* __restrict__ shift) {
    int co = blockIdx.x;
    int tid = threadIdx.x;
    float s = 0.f, q = 0.f;
    for (int i = tid; i < NCB; i += 256) {
        s += ps[(size_t)co * NCB + i];
        q += psq[(size_t)co * NCB + i];
    }
#pragma unroll
    for (int off = 32; off >= 1; off >>= 1) {
        s += __shfl_down(s, off, 64);
        q += __shfl_down(q, off, 64);
    }
    __shared__ float ss[4], qq[4];
    int w = tid >> 6, lane = tid & 63;
    if (lane == 0) { ss[w] = s; qq[w] = q; }
    __syncthreads();
    if (tid == 0) {
        float S = ss[0] + ss[1] + ss[2] + ss[3];
        float Q = qq[0] + qq[1] + qq[2] + qq[3];
        float mn = S / (float)NPOS;
        float var = Q / (float)NPOS - mn * mn;
        float rstd = rsqrtf(var + BN_EPS);
        float sc = g[co] * rstd;
        scale[co] = sc;
        shift[co] = beta[co] - mn * sc;
    }
}

// ------------------------------------------------------------ bn + leaky relu, in-place interior
// of NV consecutive 16-ch vols (one dispatch for a 32-ch split pair).
// grid = NV * 2*NPOS / 256; voli = g>>19 (2*NPOS = 2^19).
__global__ void bn_lrelu16(short* __restrict__ vol, const float* __restrict__ scale,
                           const float* __restrict__ shift) {
    int g = blockIdx.x * 256 + threadIdx.x;
    int voli = g >> 19;
    int gg = g & ((1 << 19) - 1);
    int half = gg & 1, p = gg >> 1;
    int xx = p & 31, yy = (p >> 5) & 31, zz = (p >> 10) & 15, tt = (p >> 14) & 7, bb = p >> 17;
    size_t addr = (size_t)voli * VOLE +
        ((((size_t)(bb * Tp + tt + 2) * Zp + zz + 2) * Yp + yy + 2) * Xp + xx + 2) * 16
        + half * 8;
    const int c0 = voli * 16 + half * 8;
    v8s v = *(v8s*)(vol + addr);
    short o[8];
#pragma unroll
    for (int j = 0; j < 8; ++j) {
        float f = bf2f(v[j]) * scale[c0 + j] + shift[c0 + j];
        f = f > 0.f ? f : LRELU_SLOPE * f;
        o[j] = f2bf(f);
    }
    *(v8s*)(vol + addr) = *(v8s*)o;
}

// ------------------------------------------------------------ final: bn3 + lrelu + projection
__global__ void bnproj_kernel(const short* __restrict__ h, const float* __restrict__ scale,
                              const float* __restrict__ shift, const float* __restrict__ wp,
                              const float* __restrict__ bp, float* __restrict__ out) {
    int g = blockIdx.x * 256 + threadIdx.x;
    int xx = g & 31, yy = (g >> 5) & 31, zz = (g >> 10) & 15, tt = (g >> 14) & 7, bb = g >> 17;
    size_t addr = ((((size_t)(bb * Tp + tt + 2) * Zp + zz + 2) * Yp + yy + 2) * Xp + xx + 2) * 16;
    v8s lo = *(const v8s*)(h + addr);
    v8s hi = *(const v8s*)(h + addr + 8);
    float a = bp[0];
#pragma unroll
    for (int j = 0; j < 8; ++j) {
        float f = bf2f(lo[j]) * scale[j] + shift[j];
        f = f > 0.f ? f : LRELU_SLOPE * f;
        a = fmaf(f, wp[j], a);
    }
#pragma unroll
    for (int j = 0; j < 8; ++j) {
        float f = bf2f(hi[j]) * scale[8 + j] + shift[8 + j];
        f = f > 0.f ? f : LRELU_SLOPE * f;
        a = fmaf(f, wp[8 + j], a);
    }
    out[g] = a;
}

// ------------------------------------------------------------ launch
extern "C" void kernel_launch(void* const* d_in, const int* in_sizes, int n_in,
                              void* d_out, int out_size, void* d_ws, size_t ws_size,
                              hipStream_t stream) {
    const float* x    = (const float*)d_in[0];
    const float* wemb = (const float*)d_in[1];
    const float* bemb = (const float*)d_in[2];
    const float* W1   = (const float*)d_in[3];
    const float* b1   = (const float*)d_in[4];
    const float* g1   = (const float*)d_in[5];
    const float* be1  = (const float*)d_in[6];
    const float* W2   = (const float*)d_in[7];
    const float* b2   = (const float*)d_in[8];
    const float* g2   = (const float*)d_in[9];
    const float* be2  = (const float*)d_in[10];
    const float* W3   = (const float*)d_in[11];
    const float* b3   = (const float*)d_in[12];
    const float* g3   = (const float*)d_in[13];
    const float* be3  = (const float*)d_in[14];
    const float* wp   = (const float*)d_in[15];
    const float* bp   = (const float*)d_in[16];

    char* base = (char*)d_ws;
    short* PA   = (short*)(base);                  // 16-ch vol: 19,906,560 B
    short* PB   = (short*)(base + 19906560);       // 16-ch vol: 19,906,560 B
    short* P32  = (short*)(base + 39813120);       // 2 vols: 39,813,120 B
    short* WB1  = (short*)(base + 79626240);       // 320,512 B
    short* WB2  = (short*)(base + 79946752);       // 641,024 B
    short* WB3  = (short*)(base + 80587776);       // 641,024 B
    float* ps   = (float*)(base + 81228800);       // 32*1024*4 = 131,072 B
    float* psq  = (float*)(base + 81359872);       // 131,072 B
    float* sc1  = (float*)(base + 81490944);       // 128 B each
    float* sh1  = (float*)(base + 81491072);
    float* sc2  = (float*)(base + 81491200);
    float* sh2  = (float*)(base + 81491328);
    float* sc3  = (float*)(base + 81491456);
    float* sh3  = (float*)(base + 81491584);

    // zero all padded activation volumes (pads must be 0 every call;
    // staging relies on it -> conv staging is a raw copy, no masking)
    hipMemsetAsync(base, 0, 79626240, stream);

    repack_all<<<(RNT + 255) / 256, 256, 0, stream>>>(W1, W2, W3, WB1, WB2, WB3);

    embed_kernel<<<NPOS / 256, 256, 0, stream>>>(x, wemb, bemb, PA);

    // layer 1: 16 -> 16
    conv_mfma<16, 16><<<NCB, 256, 0, stream>>>(PA, WB1, b1, PB, ps, psq);
    stats_kernel<<<16, 256, 0, stream>>>(ps, psq, g1, be1, sc1, sh1);
    bn_lrelu16<<<2 * NPOS / 256, 256, 0, stream>>>(PB, sc1, sh1);

    // layer 2: 16 -> 32 (output = 2 split 16-ch vols)
    conv_mfma<16, 32><<<NCB, 256, 0, stream>>>(PB, WB2, b2, P32, ps, psq);
    stats_kernel<<<32, 256, 0, stream>>>(ps, psq, g2, be2, sc2, sh2);
    bn_lrelu16<<<4 * NPOS / 256, 256, 0, stream>>>(P32, sc2, sh2);  // both vols, one dispatch

    // layer 3: 32 -> 16 (reads 2 split vols)
    conv_mfma<32, 16><<<NCB, 256, 0, stream>>>(P32, WB3, b3, PA, ps, psq);
    stats_kernel<<<16, 256, 0, stream>>>(ps, psq, g3, be3, sc3, sh3);

    // BN3 + lrelu + projection
    bnproj_kernel<<<NPOS / 256, 256, 0, stream>>>(PA, sc3, sh3, wp, bp, (float*)d_out);
}

// Round 15
// 445.154 us; speedup vs baseline: 1.0935x; 1.0569x over previous
//
#include <hip/hip_runtime.h>

#define LRELU_SLOPE 0.01f
#define BN_EPS 1e-5f

constexpr int B_ = 2, T_ = 8, Z_ = 16, Y_ = 32, X_ = 32;
constexpr int SP   = T_ * Z_ * Y_ * X_;   // 131072
constexpr int NPOS = B_ * SP;             // 262144
constexpr int Tp = 12, Zp = 20, Yp = 36, Xp = 36;   // padded dims (+2 each side)
constexpr int NCB  = 1024;                // conv blocks: b2 * t8 * z16 * yq4
constexpr size_t VOLE = (size_t)B_ * Tp * Zp * Yp * Xp * 16;  // shorts per 16-ch padded vol

typedef float v4f  __attribute__((ext_vector_type(4)));
typedef __bf16 v8bf __attribute__((ext_vector_type(8)));
typedef __bf16 v4bf __attribute__((ext_vector_type(4)));
typedef short  v8s  __attribute__((ext_vector_type(8)));
typedef short  v4s  __attribute__((ext_vector_type(4)));

static __device__ __forceinline__ float bf2f(short s) {
    unsigned int u = ((unsigned int)(unsigned short)s) << 16;
    float f; __builtin_memcpy(&f, &u, 4); return f;
}
static __device__ __forceinline__ short f2bf(float f) {
    unsigned int u; __builtin_memcpy(&u, &f, 4);
    u += 0x7FFF + ((u >> 16) & 1);
    return (short)(u >> 16);
}
static __device__ __forceinline__ v4f mfma16(v8bf a, v8bf b, v4f c) {
    return __builtin_amdgcn_mfma_f32_16x16x32_bf16(a, b, c, 0, 0, 0);
}

// K=16 bf16 MFMA for the unpaired 5th x-tap (kx=4). Removes the o=625
// zero-block multiply (1/6 of MFMA FLOP). Fragment layout = verified K32
// pattern scaled: lane l -> m=l&15, k=(l>>4)*4+j (=ci q*4+j).
// [r14: NT=1 port verified on HW — conv 160->143 us, MfmaUtil 45.5->51,
//  absmax bit-identical]
#if __has_builtin(__builtin_amdgcn_mfma_f32_16x16x16_bf16)
#define HAVE_K16 1
static __device__ __forceinline__ v4f mfma_k16(v4s a, v4s b, v4f c) {
    v4bf ab, bb; __builtin_memcpy(&ab, &a, 8); __builtin_memcpy(&bb, &b, 8);
    return __builtin_amdgcn_mfma_f32_16x16x16_bf16(ab, bb, c, 0, 0, 0);
}
#elif __has_builtin(__builtin_amdgcn_mfma_f32_16x16x16bf16_1k)
#define HAVE_K16 1
static __device__ __forceinline__ v4f mfma_k16(v4s a, v4s b, v4f c) {
    return __builtin_amdgcn_mfma_f32_16x16x16bf16_1k(a, b, c, 0, 0, 0);
}
#else
#define HAVE_K16 0
#endif

// async global->LDS DMA, 16 B/lane; LDS dest = wave-uniform base + lane*16
// (our staging is exactly linear: off = tid*8 shorts). Exec-masked lanes
// (off >= SLAB tail) neither load nor write.  [r9: 171.8 -> 158.7 us/conv]
static __device__ __forceinline__ void gload16(const short* g, short* l) {
    __builtin_amdgcn_global_load_lds(
        (const __attribute__((address_space(1))) void*)g,
        (__attribute__((address_space(3))) void*)l, 16, 0, 0);
}

// ------------------------------------------------------------ weight repack (all 3 layers, 1 dispatch)
// W[co][ci][625] fp32 -> WB[cih][o 626][co][16ci] bf16 (o==625 = zero block)
constexpr int RN1 = 1 * 626 * 16 * 16;   // 160256
constexpr int RN2 = 1 * 626 * 32 * 16;   // 320512
constexpr int RN3 = 2 * 626 * 16 * 16;   // 320512
constexpr int RNT = RN1 + RN2 + RN3;     // 801280 = 3130 * 256
__global__ void repack_all(const float* __restrict__ W1, const float* __restrict__ W2,
                           const float* __restrict__ W3, short* __restrict__ WB1,
                           short* __restrict__ WB2, short* __restrict__ WB3) {
    int i = blockIdx.x * 256 + threadIdx.x;
    if (i >= RNT) return;
    const float* W; short* WB; int CO, CIH, idx;
    if (i < RN1)            { W = W1; WB = WB1; CO = 16; CIH = 1; idx = i; }
    else if (i < RN1 + RN2) { W = W2; WB = WB2; CO = 32; CIH = 1; idx = i - RN1; }
    else                    { W = W3; WB = WB3; CO = 16; CIH = 2; idx = i - RN1 - RN2; }
    int cih = idx / (626 * CO * 16);
    int r   = idx % (626 * CO * 16);
    int o   = r / (CO * 16);
    int rr  = r % (CO * 16);
    int co = rr / 16, cil = rr % 16;
    WB[idx] = (o == 625) ? (short)0
            : f2bf(W[((size_t)co * (CIH * 16) + cih * 16 + cil) * 625 + o]);
}

// ------------------------------------------------------------ embed -> padded bf16 channel-last
__global__ void embed_kernel(const float* __restrict__ x, const float* __restrict__ wemb,
                             const float* __restrict__ bemb, short* __restrict__ outp) {
    int g = blockIdx.x * 256 + threadIdx.x;
    const float* xr = x + (size_t)g * 8;
    float4 xa = *(const float4*)(xr);
    float4 xb = *(const float4*)(xr + 4);
    float xv[8] = {xa.x, xa.y, xa.z, xa.w, xb.x, xb.y, xb.z, xb.w};
    int xx = g & 31, yy = (g >> 5) & 31, zz = (g >> 10) & 15, tt = (g >> 14) & 7, bb = g >> 17;
    size_t addr = ((((size_t)(bb * Tp + tt + 2) * Zp + zz + 2) * Yp + yy + 2) * Xp + xx + 2) * 16;
    short ov[16];
#pragma unroll
    for (int c = 0; c < 16; ++c) {
        float a = bemb[c];
#pragma unroll
        for (int f = 0; f < 8; ++f) a = fmaf(xv[f], wemb[f * 16 + c], a);
        ov[c] = f2bf(a);
    }
    *(v8s*)(outp + addr)     = *(v8s*)ov;
    *(v8s*)(outp + addr + 8) = *(v8s*)(ov + 8);
}

// ------------------------------------------------------------ conv4d: dbuf LDS slab, 1 barrier/phase
// Proven composition: DMA staging (r9) + balance swizzle/setprio (r2) +
// NT==1 weight hoist/fence (r11) + K16 tap-4 (r14: -10% on NT=1, verified).
// THIS ROUND: K16 tap-4 extended to NT==2 (conv2) — same zero-block
// elimination, per-g structure; Bf4[5][2] v4s = 20 VGPR replaces the g=2
// K32 group's Bf[5][2] v8bf = 40 VGPR (pressure DROPS). b64 Af4 reads cost
// ~3% bank-conflict cycles (measured r14) — net strongly positive.
// Falsified: CO-split (r3,r10), rotation (r3), YT=4 (r6,r7), BN-fusion
// (r8), compressed loop (r12).
// Block (256 thr, 4 waves) = (b,t,z,yq): out y in [yq*8,+8), x 0..31, all
// CO. Slabs s=(kt,kz)[,cih]: 25*CIH planes of 12y x 36x x 16ci (pads
// pre-zeroed in global). Double-buffered: stage slab s+1 into buf (s+1)&1 at
// top of phase s; ONE sync per phase. Wave = (xh, yw): 16x x 4y.
// Balance swizzle (verified bijective): co-resident quads sweep s4=0..3 with
// t=T0+2*s4 (sum w_t==17), z=Z0+4*s4 -> per-CU slab sums in [75,82].
template <int CI, int CO>
__global__ __launch_bounds__(256, 4) void conv_mfma(
        const short* __restrict__ inp,   // CIH padded vols, stride VOLE
        const short* __restrict__ wb,    // bf16 [CIH][626][CO][16]
        const float* __restrict__ bias,
        short* __restrict__ outp,        // CO/16 padded vols, stride VOLE
        float* __restrict__ ps, float* __restrict__ psq) {
    constexpr int NT = CO / 16;
    constexpr int CIH = CI / 16;
    constexpr int NS = 25 * CIH;
    constexpr int SLAB = 12 * 36 * 16;           // 6912 shorts
    constexpr int SLABP = SLAB + 16;             // +16: dummy-lane read overflow
    __shared__ short As[2 * SLABP];
    __shared__ float lsum[32], lsq[32];

    const int tid = threadIdx.x;
    const int w = tid >> 6, lane = tid & 63;
    const int q = lane >> 4, m = lane & 15;
    const int xh = w & 1, yw = w >> 1;
    const int blk = blockIdx.x;
    const int xl  = blk & 7;                     // XCD (round-robin model)
    const int j   = blk >> 3;                    // within-XCD index, 7 bits
    const int s4  = ((j & 3) + (j >> 5)) & 3;    // sweeps 0..3 in co-resident quads
    const int t   = (((j >> 2) & 7) + 2 * s4) & 7;
    const int z   = (((xl << 1) | ((j >> 5) & 1)) + 4 * s4) & 15;
    const int b   = j >> 6;
    const int yq  = s4;

    const int ci0 = (q & 1) * 8;
    const int sel = q >> 1;

    if (tid < 4) *(v8s*)(As + (tid >> 1) * SLABP + SLAB + (tid & 1) * 8) =
        (v8s){0,0,0,0,0,0,0,0};

    v4f acc[4][NT];
#pragma unroll
    for (int al = 0; al < 4; ++al)
#pragma unroll
        for (int nt = 0; nt < NT; ++nt) acc[al][nt] = (v4f){0.f, 0.f, 0.f, 0.f};

    auto sdec = [&](int s, int& cih, int& kt, int& kz) {
        int sl = (CIH == 2) ? (s >> 1) : s;
        cih = (CIH == 2) ? (s & 1) : 0;
        kt = sl / 5; kz = sl % 5;
    };
    auto slab_ok = [&](int s) -> bool {
        int cih, kt, kz; sdec(s, cih, kt, kz);
        int tt = t + kt, zz = z + kz;
        return tt >= 2 && tt < 10 && zz >= 2 && zz < 18;
    };
    auto stage = [&](int s, int slot) {
        int cih, kt, kz; sdec(s, cih, kt, kz);
        const short* gA = inp + (size_t)cih * VOLE +
            (((size_t)(b * Tp + t + kt) * Zp + (z + kz)) * Yp + yq * 8) * (size_t)(Xp * 16);
        short* dA = As + slot * SLABP;
#pragma unroll
        for (int r2 = 0; r2 < 4; ++r2) {
            int off = tid * 8 + r2 * 2048;
            if (off < SLAB) gload16(gA + off, dA + off);
        }
    };

    if (slab_ok(0)) stage(0, 0);
    __syncthreads();

#pragma unroll 1
    for (int s = 0; s < NS; ++s) {
        const bool nok = (s + 1 < NS) && slab_ok(s + 1);
        if (nok) stage(s + 1, (s + 1) & 1);      // DMA overlaps this phase's compute

        if (slab_ok(s)) {
            int cih, kt, kz; sdec(s, cih, kt, kz);
            const int obase = (kt * 5 + kz) * 25;
            const short* wbc = wb + (size_t)cih * 626 * (CO * 16);
            const short* Ab = As + (s & 1) * SLABP;
            __builtin_amdgcn_s_setprio(1);
#if HAVE_K16
            if constexpr (NT == 1) {
                // taps kx=0..3 via 2 K32 groups + tap kx=4 via K16 (no zero pad)
                v8bf Bfall[10];
                v4s  Bf4[5];
#pragma unroll
                for (int g = 0; g < 2; ++g) {
#pragma unroll
                    for (int ky = 0; ky < 5; ++ky) {
                        const int oq = obase + ky * 5 + 2 * g + sel;
                        Bfall[g * 5 + ky] = *(const v8bf*)(wbc + (size_t)oq * (CO * 16) +
                                                           m * 16 + ci0);
                    }
                }
#pragma unroll
                for (int ky = 0; ky < 5; ++ky) {
                    const int o4 = obase + ky * 5 + 4;
                    Bf4[ky] = *(const v4s*)(wbc + (size_t)o4 * (CO * 16) + m * 16 + q * 4);
                }
                __builtin_amdgcn_sched_barrier(0);
#pragma unroll
                for (int g = 0; g < 2; ++g) {
                    const int ax = xh * 16 + m + 2 * g + sel;
#pragma unroll
                    for (int rl = 0; rl < 8; ++rl) {
                        v8bf Af = *(const v8bf*)(Ab + ((yw * 4 + rl) * 36 + ax) * 16 + ci0);
#pragma unroll
                        for (int ky = 0; ky < 5; ++ky) {
                            const int al = rl - ky;
                            if (al >= 0 && al < 4)
                                acc[al][0] = mfma16(Af, Bfall[g * 5 + ky], acc[al][0]);
                        }
                    }
                }
                const int ax4 = xh * 16 + m + 4;
#pragma unroll
                for (int rl = 0; rl < 8; ++rl) {
                    v4s Af4 = *(const v4s*)(Ab + ((yw * 4 + rl) * 36 + ax4) * 16 + q * 4);
#pragma unroll
                    for (int ky = 0; ky < 5; ++ky) {
                        const int al = rl - ky;
                        if (al >= 0 && al < 4)
                            acc[al][0] = mfma_k16(Af4, Bf4[ky], acc[al][0]);
                    }
                }
            } else {
                // NT==2: taps kx=0..3 via per-g K32 groups, tap kx=4 via K16
                // (this round — Bf4[5][2] is HALF the register cost of the
                // old zero-padded K32 g=2 group)
#pragma unroll
                for (int g = 0; g < 2; ++g) {
                    const int kx0 = 2 * g;
                    v8bf Bf[5][NT];
#pragma unroll
                    for (int ky = 0; ky < 5; ++ky) {
                        const int oq = obase + ky * 5 + kx0 + sel;
#pragma unroll
                        for (int nt = 0; nt < NT; ++nt)
                            Bf[ky][nt] = *(const v8bf*)(wbc + (size_t)oq * (CO * 16) +
                                                        (nt * 16 + m) * 16 + ci0);
                    }
                    const int ax = xh * 16 + m + kx0 + sel;
#pragma unroll
                    for (int rl = 0; rl < 8; ++rl) {
                        v8bf Af = *(const v8bf*)(Ab + ((yw * 4 + rl) * 36 + ax) * 16 + ci0);
#pragma unroll
                        for (int ky = 0; ky < 5; ++ky) {
                            const int al = rl - ky;
                            if (al >= 0 && al < 4) {
#pragma unroll
                                for (int nt = 0; nt < NT; ++nt)
                                    acc[al][nt] = mfma16(Af, Bf[ky][nt], acc[al][nt]);
                            }
                        }
                    }
                }
                {
                    v4s Bf4[5][NT];
#pragma unroll
                    for (int ky = 0; ky < 5; ++ky) {
                        const int o4 = obase + ky * 5 + 4;
#pragma unroll
                        for (int nt = 0; nt < NT; ++nt)
                            Bf4[ky][nt] = *(const v4s*)(wbc + (size_t)o4 * (CO * 16) +
                                                        (nt * 16 + m) * 16 + q * 4);
                    }
                    const int ax4 = xh * 16 + m + 4;
#pragma unroll
                    for (int rl = 0; rl < 8; ++rl) {
                        v4s Af4 = *(const v4s*)(Ab + ((yw * 4 + rl) * 36 + ax4) * 16 + q * 4);
#pragma unroll
                        for (int ky = 0; ky < 5; ++ky) {
                            const int al = rl - ky;
                            if (al >= 0 && al < 4) {
#pragma unroll
                                for (int nt = 0; nt < NT; ++nt)
                                    acc[al][nt] = mfma_k16(Af4, Bf4[ky][nt], acc[al][nt]);
                            }
                        }
                    }
                }
            }
#else
            if constexpr (NT == 1) {
                // fallback: one latency window, 15 loads (tap-4 zero-padded)
                v8bf Bfall[15];
#pragma unroll
                for (int g = 0; g < 3; ++g) {
#pragma unroll
                    for (int ky = 0; ky < 5; ++ky) {
                        const int o0 = obase + ky * 5 + 2 * g;
                        const int od = (g < 2) ? 1 : (625 - o0);
                        const int oq = o0 + sel * od;
                        Bfall[g * 5 + ky] = *(const v8bf*)(wbc + (size_t)oq * (CO * 16) +
                                                           m * 16 + ci0);
                    }
                }
                __builtin_amdgcn_sched_barrier(0);
#pragma unroll
                for (int g = 0; g < 3; ++g) {
                    const int ax = xh * 16 + m + 2 * g + sel;
#pragma unroll
                    for (int rl = 0; rl < 8; ++rl) {
                        v8bf Af = *(const v8bf*)(Ab + ((yw * 4 + rl) * 36 + ax) * 16 + ci0);
#pragma unroll
                        for (int ky = 0; ky < 5; ++ky) {
                            const int al = rl - ky;
                            if (al >= 0 && al < 4)
                                acc[al][0] = mfma16(Af, Bfall[g * 5 + ky], acc[al][0]);
                        }
                    }
                }
            } else {
#pragma unroll
                for (int g = 0; g < 3; ++g) {
                    const int kx0 = 2 * g;
                    v8bf Bf[5][NT];
#pragma unroll
                    for (int ky = 0; ky < 5; ++ky) {
                        const int o0 = obase + ky * 5 + kx0;
                        const int od = (g < 2) ? 1 : (625 - o0);
                        const int oq = o0 + sel * od;
#pragma unroll
                        for (int nt = 0; nt < NT; ++nt)
                            Bf[ky][nt] = *(const v8bf*)(wbc + (size_t)oq * (CO * 16) +
                                                        (nt * 16 + m) * 16 + ci0);
                    }
                    const int ax = xh * 16 + m + kx0 + sel;
#pragma unroll
                    for (int rl = 0; rl < 8; ++rl) {
                        v8bf Af = *(const v8bf*)(Ab + ((yw * 4 + rl) * 36 + ax) * 16 + ci0);
#pragma unroll
                        for (int ky = 0; ky < 5; ++ky) {
                            const int al = rl - ky;
                            if (al >= 0 && al < 4) {
#pragma unroll
                                for (int nt = 0; nt < NT; ++nt)
                                    acc[al][nt] = mfma16(Af, Bf[ky][nt], acc[al][nt]);
                            }
                        }
                    }
                }
            }
#endif
            __builtin_amdgcn_s_setprio(0);
        }
        __syncthreads();                          // drains vmcnt: slab s+1 landed
    }

    // ---- epilogue: bias, bf16 store (raw) to NT padded vols, block stats
    if (tid < 32) { lsum[tid] = 0.f; lsq[tid] = 0.f; }
    __syncthreads();

    const int ybase = yq * 8 + yw * 4;
#pragma unroll
    for (int nt = 0; nt < NT; ++nt) {
        const int co = nt * 16 + m;
        const float bv = bias[co];
        float s = 0.f, sq = 0.f;
#pragma unroll
        for (int al = 0; al < 4; ++al) {
            const size_t orow = (size_t)nt * VOLE +
                ((((size_t)(b * Tp + t + 2) * Zp + (z + 2)) * Yp +
                  (ybase + al + 2)) * Xp + (xh * 16 + 2)) * 16;
#pragma unroll
            for (int rg = 0; rg < 4; ++rg) {
                float v = acc[al][nt][rg] + bv;
                outp[orow + (size_t)(q * 4 + rg) * 16 + m] = f2bf(v);
                s += v; sq += v * v;
            }
        }
        s += __shfl_down(s, 32, 64);  sq += __shfl_down(sq, 32, 64);
        s += __shfl_down(s, 16, 64);  sq += __shfl_down(sq, 16, 64);
        if (lane < 16) { atomicAdd(&lsum[co], s); atomicAdd(&lsq[co], sq); }
    }
    __syncthreads();
    if (tid < CO) {
        ps[(size_t)tid * NCB + blk]  = lsum[tid];
        psq[(size_t)tid * NCB + blk] = lsq[tid];
    }
}

// ------------------------------------------------------------ bn stats: fold into scale/shift
__global__ void stats_kernel(const float* __restrict__ ps, const float* __restrict__ psq,
                             const float* __restrict__ g, const float* __restrict__ beta,
                             float* __restrict__ scale, float* __restrict__ shift) {
    int co = blockIdx.x;
    int tid = threadIdx.x;
    float s = 0.f, q = 0.f;
    for (int i = tid; i < NCB; i += 256) {
        s += ps[(size_t)co * NCB + i];
        q += psq[(size_t)co * NCB + i];
    }
#pragma unroll
    for (int off = 32; off >= 1; off >>= 1) {
        s += __shfl_down(s, off, 64);
        q += __shfl_down(q, off, 64);
    }
    __shared__ float ss[4], qq[4];
    int w = tid >> 6, lane = tid & 63;
    if (lane == 0) { ss[w] = s; qq[w] = q; }
    __syncthreads();
    if (tid == 0) {
        float S = ss[0] + ss[1] + ss[2] + ss[3];
        float Q = qq[0] + qq[1] + qq[2] + qq[3];
        float mn = S / (float)NPOS;
        float var = Q / (float)NPOS - mn * mn;
        float rstd = rsqrtf(var + BN_EPS);
        float sc = g[co] * rstd;
        scale[co] = sc;
        shift[co] = beta[co] - mn * sc;
    }
}

// ------------------------------------------------------------ bn + leaky relu, in-place interior
// of NV consecutive 16-ch vols (one dispatch for a 32-ch split pair).
// grid = NV * 2*NPOS / 256; voli = g>>19 (2*NPOS = 2^19).
__global__ void bn_lrelu16(short* __restrict__ vol, const float* __restrict__ scale,
                           const float* __restrict__ shift) {
    int g = blockIdx.x * 256 + threadIdx.x;
    int voli = g >> 19;
    int gg = g & ((1 << 19) - 1);
    int half = gg & 1, p = gg >> 1;
    int xx = p & 31, yy = (p >> 5) & 31, zz = (p >> 10) & 15, tt = (p >> 14) & 7, bb = p >> 17;
    size_t addr = (size_t)voli * VOLE +
        ((((size_t)(bb * Tp + tt + 2) * Zp + zz + 2) * Yp + yy + 2) * Xp + xx + 2) * 16
        + half * 8;
    const int c0 = voli * 16 + half * 8;
    v8s v = *(v8s*)(vol + addr);
    short o[8];
#pragma unroll
    for (int j = 0; j < 8; ++j) {
        float f = bf2f(v[j]) * scale[c0 + j] + shift[c0 + j];
        f = f > 0.f ? f : LRELU_SLOPE * f;
        o[j] = f2bf(f);
    }
    *(v8s*)(vol + addr) = *(v8s*)o;
}

// ------------------------------------------------------------ final: bn3 + lrelu + projection
__global__ void bnproj_kernel(const short* __restrict__ h, const float* __restrict__ scale,
                              const float* __restrict__ shift, const float* __restrict__ wp,
                              const float* __restrict__ bp, float* __restrict__ out) {
    int g = blockIdx.x * 256 + threadIdx.x;
    int xx = g & 31, yy = (g >> 5) & 31, zz = (g >> 10) & 15, tt = (g >> 14) & 7, bb = g >> 17;
    size_t addr = ((((size_t)(bb * Tp + tt + 2) * Zp + zz + 2) * Yp + yy + 2) * Xp + xx + 2) * 16;
    v8s lo = *(const v8s*)(h + addr);
    v8s hi = *(const v8s*)(h + addr + 8);
    float a = bp[0];
#pragma unroll
    for (int j = 0; j < 8; ++j) {
        float f = bf2f(lo[j]) * scale[j] + shift[j];
        f = f > 0.f ? f : LRELU_SLOPE * f;
        a = fmaf(f, wp[j], a);
    }
#pragma unroll
    for (int j = 0; j < 8; ++j) {
        float f = bf2f(hi[j]) * scale[8 + j] + shift[8 + j];
        f = f > 0.f ? f : LRELU_SLOPE * f;
        a = fmaf(f, wp[8 + j], a);
    }
    out[g] = a;
}

// ------------------------------------------------------------ launch
extern "C" void kernel_launch(void* const* d_in, const int* in_sizes, int n_in,
                              void* d_out, int out_size, void* d_ws, size_t ws_size,
                              hipStream_t stream) {
    const float* x    = (const float*)d_in[0];
    const float* wemb = (const float*)d_in[1];
    const float* bemb = (const float*)d_in[2];
    const float* W1   = (const float*)d_in[3];
    const float* b1   = (const float*)d_in[4];
    const float* g1   = (const float*)d_in[5];
    const float* be1  = (const float*)d_in[6];
    const float* W2   = (const float*)d_in[7];
    const float* b2   = (const float*)d_in[8];
    const float* g2   = (const float*)d_in[9];
    const float* be2  = (const float*)d_in[10];
    const float* W3   = (const float*)d_in[11];
    const float* b3   = (const float*)d_in[12];
    const float* g3   = (const float*)d_in[13];
    const float* be3  = (const float*)d_in[14];
    const float* wp   = (const float*)d_in[15];
    const float* bp   = (const float*)d_in[16];

    char* base = (char*)d_ws;
    short* PA   = (short*)(base);                  // 16-ch vol: 19,906,560 B
    short* PB   = (short*)(base + 19906560);       // 16-ch vol: 19,906,560 B
    short* P32  = (short*)(base + 39813120);       // 2 vols: 39,813,120 B
    short* WB1  = (short*)(base + 79626240);       // 320,512 B
    short* WB2  = (short*)(base + 79946752);       // 641,024 B
    short* WB3  = (short*)(base + 80587776);       // 641,024 B
    float* ps   = (float*)(base + 81228800);       // 32*1024*4 = 131,072 B
    float* psq  = (float*)(base + 81359872);       // 131,072 B
    float* sc1  = (float*)(base + 81490944);       // 128 B each
    float* sh1  = (float*)(base + 81491072);
    float* sc2  = (float*)(base + 81491200);
    float* sh2  = (float*)(base + 81491328);
    float* sc3  = (float*)(base + 81491456);
    float* sh3  = (float*)(base + 81491584);

    // zero all padded activation volumes (pads must be 0 every call;
    // staging relies on it -> conv staging is a raw copy, no masking)
    hipMemsetAsync(base, 0, 79626240, stream);

    repack_all<<<(RNT + 255) / 256, 256, 0, stream>>>(W1, W2, W3, WB1, WB2, WB3);

    embed_kernel<<<NPOS / 256, 256, 0, stream>>>(x, wemb, bemb, PA);

    // layer 1: 16 -> 16
    conv_mfma<16, 16><<<NCB, 256, 0, stream>>>(PA, WB1, b1, PB, ps, psq);
    stats_kernel<<<16, 256, 0, stream>>>(ps, psq, g1, be1, sc1, sh1);
    bn_lrelu16<<<2 * NPOS / 256, 256, 0, stream>>>(PB, sc1, sh1);

    // layer 2: 16 -> 32 (output = 2 split 16-ch vols)
    conv_mfma<16, 32><<<NCB, 256, 0, stream>>>(PB, WB2, b2, P32, ps, psq);
    stats_kernel<<<32, 256, 0, stream>>>(ps, psq, g2, be2, sc2, sh2);
    bn_lrelu16<<<4 * NPOS / 256, 256, 0, stream>>>(P32, sc2, sh2);  // both vols, one dispatch

    // layer 3: 32 -> 16 (reads 2 split vols)
    conv_mfma<32, 16><<<NCB, 256, 0, stream>>>(P32, WB3, b3, PA, ps, psq);
    stats_kernel<<<16, 256, 0, stream>>>(ps, psq, g3, be3, sc3, sh3);

    // BN3 + lrelu + projection
    bnproj_kernel<<<NPOS / 256, 256, 0, stream>>>(PA, sc3, sh3, wp, bp, (float*)d_out);
}